// Round 1
// baseline (134.922 us; speedup 1.0000x reference)
//
#include <hip/hip_runtime.h>

// Hierarchical softmax: B=4096, NHID=512, BR=32, DEPTH=3.
// node0 = 0, node1 = 1 + lab>>10, node2 = 33 + lab>>5
// step0 = (lab>>10)&31, step1 = (lab>>5)&31, step2 = lab&31
// out[b] = prod_k softmax(x_b @ W[node_k])[step_k]

#define B_SZ 4096
#define NHID 512
#define BR 32
#define DEPTH 3

__global__ __launch_bounds__(192) void hsm_kernel(
    const float* __restrict__ inputs,
    const int* __restrict__ labels,
    const float* __restrict__ W,
    float* __restrict__ out)
{
    __shared__ float xs[NHID];
    __shared__ float pk[DEPTH];

    const int b = blockIdx.x;
    const int tid = threadIdx.x;

    // Stage x[b] into LDS (128 float4 loads, threads 0..127)
    if (tid < NHID / 4) {
        ((float4*)xs)[tid] = ((const float4*)(inputs + (size_t)b * NHID))[tid];
    }
    __syncthreads();

    const int k    = tid >> 6;   // wave index = tree level (0..2)
    const int lane = tid & 63;
    const int lab  = labels[b];

    int node, step;
    if (k == 0)      { node = 0;                 step = (lab >> 10) & 31; }
    else if (k == 1) { node = 1 + (lab >> 10);   step = (lab >> 5)  & 31; }
    else             { node = 33 + (lab >> 5);   step = lab & 31;         }

    // Lane layout: col group (4 cols) = lane&7, h-strip = lane>>3 (h = strip + 8*i)
    const int colg  = lane & 7;
    const int hbase = lane >> 3;
    const float4* wp = (const float4*)(W + (size_t)node * (NHID * BR) + hbase * BR + colg * 4);

    float a0 = 0.f, a1 = 0.f, a2 = 0.f, a3 = 0.f;
    #pragma unroll 8
    for (int i = 0; i < NHID / 8; ++i) {
        float4 w = wp[i * (8 * BR / 4)];   // stride 8 h-rows = 64 float4
        float  x = xs[hbase + 8 * i];
        a0 = fmaf(x, w.x, a0);
        a1 = fmaf(x, w.y, a1);
        a2 = fmaf(x, w.z, a2);
        a3 = fmaf(x, w.w, a3);
    }

    // Butterfly reduce over the 8 h-strips (xor masks 8,16,32): every lane
    // ends with the full dot products for its 4 columns (group = lane&7).
    for (int m = 8; m <= 32; m <<= 1) {
        a0 += __shfl_xor(a0, m);
        a1 += __shfl_xor(a1, m);
        a2 += __shfl_xor(a2, m);
        a3 += __shfl_xor(a3, m);
    }

    // Softmax over 32 logits spread as 8 groups x 4 values.
    float mx = fmaxf(fmaxf(a0, a1), fmaxf(a2, a3));
    for (int m = 1; m <= 4; m <<= 1) mx = fmaxf(mx, __shfl_xor(mx, m));
    float es = expf(a0 - mx) + expf(a1 - mx) + expf(a2 - mx) + expf(a3 - mx);
    for (int m = 1; m <= 4; m <<= 1) es += __shfl_xor(es, m);

    // Fetch logit[step]: lane (step>>2) (lanes 0..7 have group == lane) holds it.
    const int e = step & 3;
    float v = (e == 0) ? a0 : (e == 1) ? a1 : (e == 2) ? a2 : a3;
    float sl = __shfl(v, step >> 2);

    float p = __expf(sl - mx) / es;
    // recompute with expf (not __expf) for accuracy: threshold is tight-ish
    p = expf(sl - mx) / es;

    if (lane == 0) pk[k] = p;
    __syncthreads();
    if (tid == 0) out[b] = pk[0] * pk[1] * pk[2];
}

extern "C" void kernel_launch(void* const* d_in, const int* in_sizes, int n_in,
                              void* d_out, int out_size, void* d_ws, size_t ws_size,
                              hipStream_t stream)
{
    const float* inputs = (const float*)d_in[0];
    const int*   labels = (const int*)d_in[1];
    const float* W      = (const float*)d_in[2];
    float* out = (float*)d_out;

    hsm_kernel<<<dim3(B_SZ), dim3(192), 0, stream>>>(inputs, labels, W, out);
}